// Round 1
// baseline (414.403 us; speedup 1.0000x reference)
//
#include <hip/hip_runtime.h>
#include <math.h>

#define BB 32
#define TT 100
#define VV 10000
#define DD 128
#define OUTN 1000
#define G3 384

// ---------------------------------------------------------------------------
// K1: sparse embedding sum  e[b,t,:] = sum_{v: x!=0} x[b,t,v] * emb[v,:]
// grid = B*T blocks, 256 threads
// ---------------------------------------------------------------------------
__global__ __launch_bounds__(256) void k_embed(
    const float* __restrict__ x, const float* __restrict__ emb,
    float* __restrict__ e, int* __restrict__ mask)
{
    const int bt  = blockIdx.x;
    const int tid = threadIdx.x;
    __shared__ int   s_cnt;
    __shared__ int   s_any;
    __shared__ int   s_idx[256];
    __shared__ float s_val[256];
    if (tid == 0) { s_cnt = 0; s_any = 0; }
    __syncthreads();

    const float4* x4 = (const float4*)(x + (size_t)bt * VV);
    for (int i = tid; i < VV / 4; i += 256) {
        float4 v = x4[i];
        if (v.x != 0.f) { int p = atomicAdd(&s_cnt, 1); if (p < 256) { s_idx[p] = 4*i+0; s_val[p] = v.x; } }
        if (v.y != 0.f) { int p = atomicAdd(&s_cnt, 1); if (p < 256) { s_idx[p] = 4*i+1; s_val[p] = v.y; } }
        if (v.z != 0.f) { int p = atomicAdd(&s_cnt, 1); if (p < 256) { s_idx[p] = 4*i+2; s_val[p] = v.z; } }
        if (v.w != 0.f) { int p = atomicAdd(&s_cnt, 1); if (p < 256) { s_idx[p] = 4*i+3; s_val[p] = v.w; } }
    }
    __syncthreads();
    int cnt = s_cnt; if (cnt > 256) cnt = 256;
    if (tid < DD) {
        float acc = 0.f;
        for (int i = 0; i < cnt; ++i)
            acc += s_val[i] * emb[(size_t)s_idx[i] * DD + tid];
        e[(size_t)bt * DD + tid] = acc;
        if (acc != 0.f) s_any = 1;
    }
    __syncthreads();
    if (tid == 0) mask[bt] = s_any;
}

// ---------------------------------------------------------------------------
// K2: input-side gates  x3[row, 0:384]=e@wih_f^T+bih_f ; x3[row,384:768]=e@wih_b^T+bih_b
// grid = 400 blocks (8 rows each), 256 threads; each thread 3 cols x 8 rows
// ---------------------------------------------------------------------------
__global__ __launch_bounds__(256) void k_gates(
    const float* __restrict__ e,
    const float* __restrict__ wih_f, const float* __restrict__ bih_f,
    const float* __restrict__ wih_b, const float* __restrict__ bih_b,
    float* __restrict__ x3)
{
    const int r0  = blockIdx.x * 8;
    const int tid = threadIdx.x;
    __shared__ __align__(16) float se[8][DD];
    for (int i = tid; i < 8 * DD; i += 256)
        se[i >> 7][i & 127] = e[(size_t)(r0 + (i >> 7)) * DD + (i & 127)];
    __syncthreads();

    for (int cc = 0; cc < 3; ++cc) {
        const int col = tid + cc * 256;                 // 0..767
        const float* wrow;
        float bias;
        if (col < G3) { wrow = wih_f + (size_t)col * DD;        bias = bih_f[col]; }
        else          { wrow = wih_b + (size_t)(col - G3) * DD; bias = bih_b[col - G3]; }
        float acc[8];
        #pragma unroll
        for (int r = 0; r < 8; ++r) acc[r] = 0.f;
        const float4* w4 = (const float4*)wrow;
        for (int k4 = 0; k4 < DD / 4; ++k4) {
            float4 w = w4[k4];
            #pragma unroll
            for (int r = 0; r < 8; ++r) {
                float4 ev = *(const float4*)&se[r][4 * k4];
                acc[r] += ev.x * w.x + ev.y * w.y + ev.z * w.z + ev.w * w.w;
            }
        }
        #pragma unroll
        for (int r = 0; r < 8; ++r)
            x3[(size_t)(r0 + r) * 768 + col] = acc[r] + bias;
    }
}

// ---------------------------------------------------------------------------
// K3: GRU, one block per (batch, dir). 384 threads.
// v2: (1) whh row truly register-resident: float4 W[32], full unroll,
//     __launch_bounds__(384,2) -> 256-VGPR budget (6 waves/block = 2/EU peak).
//     Before: VGPR_Count=84 proved w[] was scratch-resident -> ~196 KB/CU of
//     weight re-fetch per timestep.
// (2) 8 accumulators: dependent-FMA chain 128*4 -> ~16*4 cycles.
// (3) fast sigmoid/tanh via __expf + v_rcp (overflow-safe tanh form).
// ---------------------------------------------------------------------------
__global__ __launch_bounds__(384, 2) void k_gru(
    const float* __restrict__ x3,
    const float* __restrict__ whh_f, const float* __restrict__ bhh_f,
    const float* __restrict__ whh_b, const float* __restrict__ bhh_b,
    float* __restrict__ h_all)
{
    const int dir = blockIdx.x & 1;
    const int b   = blockIdx.x >> 1;
    const int g   = threadIdx.x;           // 0..383
    const float* whh = dir ? whh_b : whh_f;
    const float* bhh = dir ? bhh_b : bhh_f;

    // weight row -> VGPRs (128 floats = 32 float4, all indices compile-time)
    float4 W[32];
    {
        const float4* wr4 = (const float4*)(whh + (size_t)g * DD);
        #pragma unroll
        for (int j = 0; j < 32; ++j) W[j] = wr4[j];
    }
    const float bh = bhh[g];

    __shared__ __align__(16) float h_lds[DD];
    __shared__ float gh_lds[G3];
    float h_reg = 0.f;
    if (g < DD) h_lds[g] = 0.f;
    __syncthreads();

    for (int t = 0; t < TT; ++t) {
        const int te = dir ? (TT - 1 - t) : t;
        const float* x3p = x3 + (size_t)(b * TT + te) * 768 + dir * G3;
        float xr = 0.f, xz = 0.f, xn = 0.f;
        if (g < DD) { xr = x3p[g]; xz = x3p[DD + g]; xn = x3p[2 * DD + g]; }

        // gh[g] = dot(whh[g,:], h) + bhh[g], 8 independent chains
        float acc[8];
        #pragma unroll
        for (int i = 0; i < 8; ++i) acc[i] = 0.f;
        #pragma unroll
        for (int j = 0; j < 32; ++j) {
            float4 hv = *(const float4*)&h_lds[4 * j];   // uniform addr -> LDS broadcast
            float4 wv = W[j];
            acc[j & 7] += wv.x * hv.x + wv.y * hv.y + wv.z * hv.z + wv.w * hv.w;
        }
        gh_lds[g] = ((acc[0] + acc[1]) + (acc[2] + acc[3]))
                  + ((acc[4] + acc[5]) + (acc[6] + acc[7])) + bh;
        __syncthreads();

        if (g < DD) {
            float hr = gh_lds[g], hz = gh_lds[DD + g], hn = gh_lds[2 * DD + g];
            float r  = __builtin_amdgcn_rcpf(1.f + __expf(-(xr + hr)));
            float z  = __builtin_amdgcn_rcpf(1.f + __expf(-(xz + hz)));
            // tanh(x) = 1 - 2/(e^(2x)+1): safe at +/-inf (e2=inf -> 1, e2=0 -> -1)
            float e2 = __expf(2.f * (xn + r * hn));
            float n  = 1.f - 2.f * __builtin_amdgcn_rcpf(e2 + 1.f);
            float hnew = n + z * (h_reg - n);            // == (1-z)*n + z*h
            h_reg = hnew;
            h_lds[g] = hnew;
            h_all[(size_t)((dir * BB + b) * TT + te) * DD + g] = hnew;
        }
        __syncthreads();
    }
}

// ---------------------------------------------------------------------------
// K4a: per-batch attention + h_last + combine -> feat[b,128]
// ---------------------------------------------------------------------------
__global__ __launch_bounds__(256) void k_attn(
    const float* __restrict__ h_all, const int* __restrict__ mask,
    const float* __restrict__ attn_w, const float* __restrict__ attn_b,
    const float* __restrict__ comb_w, const float* __restrict__ comb_b,
    float* __restrict__ feat)
{
    const int b   = blockIdx.x;
    const int tid = threadIdx.x;
    __shared__ float s_aw[256];
    __shared__ float s_sc[128];
    __shared__ int   s_m[128];
    __shared__ float s_red[128];
    __shared__ __align__(16) float s_ch[512];

    s_aw[tid] = attn_w[tid];
    int m = 0;
    if (tid < 128) {
        m = (tid < TT) ? mask[b * TT + tid] : 0;
        s_m[tid] = m;
    }
    __syncthreads();
    for (int s = 64; s > 0; s >>= 1) {
        if (tid < s) s_m[tid] += s_m[tid + s];
        __syncthreads();
    }
    const int last = s_m[0] - 1;

    const float* hf = h_all + (size_t)(0 * BB + b) * TT * DD;
    const float* hb = h_all + (size_t)(1 * BB + b) * TT * DD;

    float sc = -1e9f;
    if (tid < TT) {
        float a = attn_b[0];
        const float4* hf4 = (const float4*)(hf + (size_t)tid * DD);
        const float4* hb4 = (const float4*)(hb + (size_t)tid * DD);
        for (int k = 0; k < DD / 4; ++k) {
            float4 v = hf4[k];
            a += v.x * s_aw[4*k] + v.y * s_aw[4*k+1] + v.z * s_aw[4*k+2] + v.w * s_aw[4*k+3];
        }
        for (int k = 0; k < DD / 4; ++k) {
            float4 v = hb4[k];
            a += v.x * s_aw[DD+4*k] + v.y * s_aw[DD+4*k+1] + v.z * s_aw[DD+4*k+2] + v.w * s_aw[DD+4*k+3];
        }
        sc = m ? a : -1e9f;
    }
    if (tid < 128) { s_sc[tid] = sc; s_red[tid] = sc; }
    __syncthreads();
    for (int s = 64; s > 0; s >>= 1) {
        if (tid < s) s_red[tid] = fmaxf(s_red[tid], s_red[tid + s]);
        __syncthreads();
    }
    const float mx = s_red[0];
    __syncthreads();
    float ex = 0.f;
    if (tid < 128) { ex = __expf(s_sc[tid] - mx); s_sc[tid] = ex; s_red[tid] = ex; }
    __syncthreads();
    for (int s = 64; s > 0; s >>= 1) {
        if (tid < s) s_red[tid] += s_red[tid + s];
        __syncthreads();
    }
    const float inv = 1.f / s_red[0];
    __syncthreads();

    {
        const int fl = tid & 127;
        const float* hp = (tid < 128) ? hf : hb;
        float csum = 0.f;
        for (int t = 0; t < TT; ++t)
            csum += s_sc[t] * hp[(size_t)t * DD + fl];
        s_ch[tid]       = csum * inv;
        s_ch[256 + tid] = hp[(size_t)last * DD + fl];
    }
    __syncthreads();

    if (tid < 128) {
        float a = comb_b[tid];
        const float4* cw = (const float4*)(comb_w + (size_t)tid * 512);
        for (int k = 0; k < 128; ++k) {
            float4 w4 = cw[k];
            float4 v4 = *(const float4*)&s_ch[4 * k];
            a += w4.x * v4.x + w4.y * v4.y + w4.z * v4.z + w4.w * v4.w;
        }
        feat[(size_t)b * DD + tid] = tanhf(a);
    }
}

// ---------------------------------------------------------------------------
// K4b: logits = feat @ fc_w^T + fc_b   grid = B*4 blocks, 256 threads
// ---------------------------------------------------------------------------
__global__ __launch_bounds__(256) void k_logits(
    const float* __restrict__ feat, const float* __restrict__ fc_w,
    const float* __restrict__ fc_b, float* __restrict__ out)
{
    const int b   = blockIdx.x >> 2;
    const int oc  = blockIdx.x & 3;
    const int tid = threadIdx.x;
    const int o   = oc * 256 + tid;
    __shared__ __align__(16) float s_f[DD];
    if (tid < DD) s_f[tid] = feat[(size_t)b * DD + tid];
    __syncthreads();
    if (o < OUTN) {
        float a = fc_b[o];
        const float4* w4 = (const float4*)(fc_w + (size_t)o * DD);
        for (int k = 0; k < DD / 4; ++k) {
            float4 w = w4[k];
            float4 v = *(const float4*)&s_f[4 * k];
            a += w.x * v.x + w.y * v.y + w.z * v.z + w.w * v.w;
        }
        out[(size_t)b * OUTN + o] = a;
    }
}

// ---------------------------------------------------------------------------
extern "C" void kernel_launch(void* const* d_in, const int* in_sizes, int n_in,
                              void* d_out, int out_size, void* d_ws, size_t ws_size,
                              hipStream_t stream)
{
    const float* x      = (const float*)d_in[0];
    const float* emb    = (const float*)d_in[1];
    const float* wih_f  = (const float*)d_in[2];
    const float* whh_f  = (const float*)d_in[3];
    const float* bih_f  = (const float*)d_in[4];
    const float* bhh_f  = (const float*)d_in[5];
    const float* wih_b  = (const float*)d_in[6];
    const float* whh_b  = (const float*)d_in[7];
    const float* bih_b  = (const float*)d_in[8];
    const float* bhh_b  = (const float*)d_in[9];
    const float* attn_w = (const float*)d_in[10];
    const float* attn_b = (const float*)d_in[11];
    const float* comb_w = (const float*)d_in[12];
    const float* comb_b = (const float*)d_in[13];
    const float* fc_w   = (const float*)d_in[14];
    const float* fc_b   = (const float*)d_in[15];
    float* out = (float*)d_out;

    // workspace layout (floats)
    float* ws    = (float*)d_ws;
    float* e     = ws;                    // 409600
    int*   mask  = (int*)(ws + 409600);   // 3200
    float* x3    = ws + 412800;           // 2457600
    float* h_all = ws + 2870400;          // 819200
    float* feat  = ws + 3689600;          // 4096   (total ~14.1 MB)

    k_embed <<<BB * TT,      256, 0, stream>>>(x, emb, e, mask);
    k_gates <<<(BB * TT)/8,  256, 0, stream>>>(e, wih_f, bih_f, wih_b, bih_b, x3);
    k_gru   <<<2 * BB,       384, 0, stream>>>(x3, whh_f, bhh_f, whh_b, bhh_b, h_all);
    k_attn  <<<BB,           256, 0, stream>>>(h_all, mask, attn_w, attn_b, comb_w, comb_b, feat);
    k_logits<<<BB * 4,       256, 0, stream>>>(feat, fc_w, fc_b, out);
}

// Round 2
// 372.887 us; speedup vs baseline: 1.1113x; 1.1113x over previous
//
#include <hip/hip_runtime.h>
#include <math.h>

#define BB 32
#define TT 100
#define VV 10000
#define DD 128
#define OUTN 1000
#define G3 384

// ---------------------------------------------------------------------------
// K1: sparse embedding sum  e[b,t,:] = sum_{v: x!=0} x[b,t,v] * emb[v,:]
// grid = B*T blocks, 256 threads
// ---------------------------------------------------------------------------
__global__ __launch_bounds__(256) void k_embed(
    const float* __restrict__ x, const float* __restrict__ emb,
    float* __restrict__ e, int* __restrict__ mask)
{
    const int bt  = blockIdx.x;
    const int tid = threadIdx.x;
    __shared__ int   s_cnt;
    __shared__ int   s_any;
    __shared__ int   s_idx[256];
    __shared__ float s_val[256];
    if (tid == 0) { s_cnt = 0; s_any = 0; }
    __syncthreads();

    const float4* x4 = (const float4*)(x + (size_t)bt * VV);
    for (int i = tid; i < VV / 4; i += 256) {
        float4 v = x4[i];
        if (v.x != 0.f) { int p = atomicAdd(&s_cnt, 1); if (p < 256) { s_idx[p] = 4*i+0; s_val[p] = v.x; } }
        if (v.y != 0.f) { int p = atomicAdd(&s_cnt, 1); if (p < 256) { s_idx[p] = 4*i+1; s_val[p] = v.y; } }
        if (v.z != 0.f) { int p = atomicAdd(&s_cnt, 1); if (p < 256) { s_idx[p] = 4*i+2; s_val[p] = v.z; } }
        if (v.w != 0.f) { int p = atomicAdd(&s_cnt, 1); if (p < 256) { s_idx[p] = 4*i+3; s_val[p] = v.w; } }
    }
    __syncthreads();
    int cnt = s_cnt; if (cnt > 256) cnt = 256;
    if (tid < DD) {
        float acc = 0.f;
        for (int i = 0; i < cnt; ++i)
            acc += s_val[i] * emb[(size_t)s_idx[i] * DD + tid];
        e[(size_t)bt * DD + tid] = acc;
        if (acc != 0.f) s_any = 1;
    }
    __syncthreads();
    if (tid == 0) mask[bt] = s_any;
}

// ---------------------------------------------------------------------------
// K2: input-side gates  x3[row, 0:384]=e@wih_f^T+bih_f ; x3[row,384:768]=e@wih_b^T+bih_b
// grid = 400 blocks (8 rows each), 256 threads; each thread 3 cols x 8 rows
// ---------------------------------------------------------------------------
__global__ __launch_bounds__(256) void k_gates(
    const float* __restrict__ e,
    const float* __restrict__ wih_f, const float* __restrict__ bih_f,
    const float* __restrict__ wih_b, const float* __restrict__ bih_b,
    float* __restrict__ x3)
{
    const int r0  = blockIdx.x * 8;
    const int tid = threadIdx.x;
    __shared__ __align__(16) float se[8][DD];
    for (int i = tid; i < 8 * DD; i += 256)
        se[i >> 7][i & 127] = e[(size_t)(r0 + (i >> 7)) * DD + (i & 127)];
    __syncthreads();

    for (int cc = 0; cc < 3; ++cc) {
        const int col = tid + cc * 256;                 // 0..767
        const float* wrow;
        float bias;
        if (col < G3) { wrow = wih_f + (size_t)col * DD;        bias = bih_f[col]; }
        else          { wrow = wih_b + (size_t)(col - G3) * DD; bias = bih_b[col - G3]; }
        float acc[8];
        #pragma unroll
        for (int r = 0; r < 8; ++r) acc[r] = 0.f;
        const float4* w4 = (const float4*)wrow;
        for (int k4 = 0; k4 < DD / 4; ++k4) {
            float4 w = w4[k4];
            #pragma unroll
            for (int r = 0; r < 8; ++r) {
                float4 ev = *(const float4*)&se[r][4 * k4];
                acc[r] += ev.x * w.x + ev.y * w.y + ev.z * w.z + ev.w * w.w;
            }
        }
        #pragma unroll
        for (int r = 0; r < 8; ++r)
            x3[(size_t)(r0 + r) * 768 + col] = acc[r] + bias;
    }
}

// ---------------------------------------------------------------------------
// K3: GRU v3. One block per (batch, dir). 256 threads = (g in 0..127) x (k-half).
// - Weights as 48 NAMED float4s (no array => SROA must promote; v1/v2's arrays
//   went to scratch: VGPR_Count was 84/92 < the 128 floats of weights).
// - Each thread: partial dots for 3 gate outputs (r,z,n of dim g) over 64 k's.
//   One ds_read_b128 feeds 12 FMAs => DS instrs/step 192 -> ~78.
// - launch_bounds(256,1): 1 wave/EU min => 512-VGPR budget, no spill pressure.
// ---------------------------------------------------------------------------
__global__ __launch_bounds__(256, 1) void k_gru(
    const float* __restrict__ x3,
    const float* __restrict__ whh_f, const float* __restrict__ bhh_f,
    const float* __restrict__ whh_b, const float* __restrict__ bhh_b,
    float* __restrict__ h_all)
{
    const int dir = blockIdx.x & 1;
    const int b   = blockIdx.x >> 1;
    const int tid = threadIdx.x;       // 0..255
    const int g   = tid & 127;         // output dim
    const int kh  = tid >> 7;          // k-half team: 0 or 1
    const int kb  = kh * 64;           // k base
    const float* whh = dir ? whh_b : whh_f;
    const float* bhh = dir ? bhh_b : bhh_f;

    const float4* pr4 = (const float4*)(whh + (size_t)(g         ) * DD + kb);
    const float4* pz4 = (const float4*)(whh + (size_t)(DD     + g) * DD + kb);
    const float4* pn4 = (const float4*)(whh + (size_t)(2 * DD + g) * DD + kb);

#define Q16(M) M(0) M(1) M(2) M(3) M(4) M(5) M(6) M(7) M(8) M(9) M(10) M(11) M(12) M(13) M(14) M(15)
#define DECLW(i) float4 wr##i = pr4[i], wz##i = pz4[i], wn##i = pn4[i];
    Q16(DECLW)

    const float bhr = bhh[g], bhz = bhh[DD + g], bhn = bhh[2 * DD + g];

    __shared__ __align__(16) float h_lds[DD];
    __shared__ float p_lds[3 * DD];
    float h_reg = 0.f;
    if (tid < DD) h_lds[tid] = 0.f;
    __syncthreads();

    for (int t = 0; t < TT; ++t) {
        const int te = dir ? (TT - 1 - t) : t;
        const float* x3p = x3 + (size_t)(b * TT + te) * 768 + dir * G3;
        float xr = 0.f, xz = 0.f, xn = 0.f;
        if (tid < DD) { xr = x3p[g]; xz = x3p[DD + g]; xn = x3p[2 * DD + g]; }

        // partial dots over this thread's k-half; 6 independent FMA chains
        float ar0 = 0.f, ar1 = 0.f, az0 = 0.f, az1 = 0.f, an0 = 0.f, an1 = 0.f;
#define FMA(i) { float4 hv = *(const float4*)&h_lds[kb + 4 * (i)]; \
        (((i)&1) ? ar1 : ar0) += wr##i.x*hv.x + wr##i.y*hv.y + wr##i.z*hv.z + wr##i.w*hv.w; \
        (((i)&1) ? az1 : az0) += wz##i.x*hv.x + wz##i.y*hv.y + wz##i.z*hv.z + wz##i.w*hv.w; \
        (((i)&1) ? an1 : an0) += wn##i.x*hv.x + wn##i.y*hv.y + wn##i.z*hv.z + wn##i.w*hv.w; }
        Q16(FMA)
#undef FMA
        const float pr = ar0 + ar1, pz = az0 + az1, pn = an0 + an1;

        if (kh) { p_lds[g] = pr; p_lds[DD + g] = pz; p_lds[2 * DD + g] = pn; }
        __syncthreads();

        if (tid < DD) {
            float hr = pr + p_lds[g]          + bhr;
            float hz = pz + p_lds[DD + g]     + bhz;
            float hn = pn + p_lds[2 * DD + g] + bhn;
            float r  = __builtin_amdgcn_rcpf(1.f + __expf(-(xr + hr)));
            float z  = __builtin_amdgcn_rcpf(1.f + __expf(-(xz + hz)));
            // tanh(x) = 1 - 2/(e^(2x)+1): safe at +/-inf
            float e2 = __expf(2.f * (xn + r * hn));
            float n  = 1.f - 2.f * __builtin_amdgcn_rcpf(e2 + 1.f);
            float hnew = n + z * (h_reg - n);            // == (1-z)*n + z*h
            h_reg = hnew;
            h_lds[g] = hnew;
            h_all[(size_t)((dir * BB + b) * TT + te) * DD + g] = hnew;
        }
        __syncthreads();
    }
#undef DECLW
#undef Q16
}

// ---------------------------------------------------------------------------
// K4a: per-batch attention + h_last + combine -> feat[b,128]
// ---------------------------------------------------------------------------
__global__ __launch_bounds__(256) void k_attn(
    const float* __restrict__ h_all, const int* __restrict__ mask,
    const float* __restrict__ attn_w, const float* __restrict__ attn_b,
    const float* __restrict__ comb_w, const float* __restrict__ comb_b,
    float* __restrict__ feat)
{
    const int b   = blockIdx.x;
    const int tid = threadIdx.x;
    __shared__ float s_aw[256];
    __shared__ float s_sc[128];
    __shared__ int   s_m[128];
    __shared__ float s_red[128];
    __shared__ __align__(16) float s_ch[512];

    s_aw[tid] = attn_w[tid];
    int m = 0;
    if (tid < 128) {
        m = (tid < TT) ? mask[b * TT + tid] : 0;
        s_m[tid] = m;
    }
    __syncthreads();
    for (int s = 64; s > 0; s >>= 1) {
        if (tid < s) s_m[tid] += s_m[tid + s];
        __syncthreads();
    }
    const int last = s_m[0] - 1;

    const float* hf = h_all + (size_t)(0 * BB + b) * TT * DD;
    const float* hb = h_all + (size_t)(1 * BB + b) * TT * DD;

    float sc = -1e9f;
    if (tid < TT) {
        float a = attn_b[0];
        const float4* hf4 = (const float4*)(hf + (size_t)tid * DD);
        const float4* hb4 = (const float4*)(hb + (size_t)tid * DD);
        for (int k = 0; k < DD / 4; ++k) {
            float4 v = hf4[k];
            a += v.x * s_aw[4*k] + v.y * s_aw[4*k+1] + v.z * s_aw[4*k+2] + v.w * s_aw[4*k+3];
        }
        for (int k = 0; k < DD / 4; ++k) {
            float4 v = hb4[k];
            a += v.x * s_aw[DD+4*k] + v.y * s_aw[DD+4*k+1] + v.z * s_aw[DD+4*k+2] + v.w * s_aw[DD+4*k+3];
        }
        sc = m ? a : -1e9f;
    }
    if (tid < 128) { s_sc[tid] = sc; s_red[tid] = sc; }
    __syncthreads();
    for (int s = 64; s > 0; s >>= 1) {
        if (tid < s) s_red[tid] = fmaxf(s_red[tid], s_red[tid + s]);
        __syncthreads();
    }
    const float mx = s_red[0];
    __syncthreads();
    float ex = 0.f;
    if (tid < 128) { ex = __expf(s_sc[tid] - mx); s_sc[tid] = ex; s_red[tid] = ex; }
    __syncthreads();
    for (int s = 64; s > 0; s >>= 1) {
        if (tid < s) s_red[tid] += s_red[tid + s];
        __syncthreads();
    }
    const float inv = 1.f / s_red[0];
    __syncthreads();

    {
        const int fl = tid & 127;
        const float* hp = (tid < 128) ? hf : hb;
        float csum = 0.f;
        for (int t = 0; t < TT; ++t)
            csum += s_sc[t] * hp[(size_t)t * DD + fl];
        s_ch[tid]       = csum * inv;
        s_ch[256 + tid] = hp[(size_t)last * DD + fl];
    }
    __syncthreads();

    if (tid < 128) {
        float a = comb_b[tid];
        const float4* cw = (const float4*)(comb_w + (size_t)tid * 512);
        for (int k = 0; k < 128; ++k) {
            float4 w4 = cw[k];
            float4 v4 = *(const float4*)&s_ch[4 * k];
            a += w4.x * v4.x + w4.y * v4.y + w4.z * v4.z + w4.w * v4.w;
        }
        feat[(size_t)b * DD + tid] = tanhf(a);
    }
}

// ---------------------------------------------------------------------------
// K4b: logits = feat @ fc_w^T + fc_b   grid = B*4 blocks, 256 threads
// ---------------------------------------------------------------------------
__global__ __launch_bounds__(256) void k_logits(
    const float* __restrict__ feat, const float* __restrict__ fc_w,
    const float* __restrict__ fc_b, float* __restrict__ out)
{
    const int b   = blockIdx.x >> 2;
    const int oc  = blockIdx.x & 3;
    const int tid = threadIdx.x;
    const int o   = oc * 256 + tid;
    __shared__ __align__(16) float s_f[DD];
    if (tid < DD) s_f[tid] = feat[(size_t)b * DD + tid];
    __syncthreads();
    if (o < OUTN) {
        float a = fc_b[o];
        const float4* w4 = (const float4*)(fc_w + (size_t)o * DD);
        for (int k = 0; k < DD / 4; ++k) {
            float4 w = w4[k];
            float4 v = *(const float4*)&s_f[4 * k];
            a += w.x * v.x + w.y * v.y + w.z * v.z + w.w * v.w;
        }
        out[(size_t)b * OUTN + o] = a;
    }
}

// ---------------------------------------------------------------------------
extern "C" void kernel_launch(void* const* d_in, const int* in_sizes, int n_in,
                              void* d_out, int out_size, void* d_ws, size_t ws_size,
                              hipStream_t stream)
{
    const float* x      = (const float*)d_in[0];
    const float* emb    = (const float*)d_in[1];
    const float* wih_f  = (const float*)d_in[2];
    const float* whh_f  = (const float*)d_in[3];
    const float* bih_f  = (const float*)d_in[4];
    const float* bhh_f  = (const float*)d_in[5];
    const float* wih_b  = (const float*)d_in[6];
    const float* whh_b  = (const float*)d_in[7];
    const float* bih_b  = (const float*)d_in[8];
    const float* bhh_b  = (const float*)d_in[9];
    const float* attn_w = (const float*)d_in[10];
    const float* attn_b = (const float*)d_in[11];
    const float* comb_w = (const float*)d_in[12];
    const float* comb_b = (const float*)d_in[13];
    const float* fc_w   = (const float*)d_in[14];
    const float* fc_b   = (const float*)d_in[15];
    float* out = (float*)d_out;

    // workspace layout (floats)
    float* ws    = (float*)d_ws;
    float* e     = ws;                    // 409600
    int*   mask  = (int*)(ws + 409600);   // 3200
    float* x3    = ws + 412800;           // 2457600
    float* h_all = ws + 2870400;          // 819200
    float* feat  = ws + 3689600;          // 4096   (total ~14.1 MB)

    k_embed <<<BB * TT,      256, 0, stream>>>(x, emb, e, mask);
    k_gates <<<(BB * TT)/8,  256, 0, stream>>>(e, wih_f, bih_f, wih_b, bih_b, x3);
    k_gru   <<<2 * BB,       256, 0, stream>>>(x3, whh_f, bhh_f, whh_b, bhh_b, h_all);
    k_attn  <<<BB,           256, 0, stream>>>(h_all, mask, attn_w, attn_b, comb_w, comb_b, feat);
    k_logits<<<BB * 4,       256, 0, stream>>>(feat, fc_w, fc_b, out);
}

// Round 3
// 351.555 us; speedup vs baseline: 1.1788x; 1.0607x over previous
//
#include <hip/hip_runtime.h>
#include <math.h>

#define BB 32
#define TT 100
#define VV 10000
#define DD 128
#define OUTN 1000
#define G3 384

// ---------------------------------------------------------------------------
// K1: sparse embedding sum  e[b,t,:] = sum_{v: x!=0} x[b,t,v] * emb[v,:]
// grid = B*T blocks, 256 threads
// ---------------------------------------------------------------------------
__global__ __launch_bounds__(256) void k_embed(
    const float* __restrict__ x, const float* __restrict__ emb,
    float* __restrict__ e, int* __restrict__ mask)
{
    const int bt  = blockIdx.x;
    const int tid = threadIdx.x;
    __shared__ int   s_cnt;
    __shared__ int   s_any;
    __shared__ int   s_idx[256];
    __shared__ float s_val[256];
    if (tid == 0) { s_cnt = 0; s_any = 0; }
    __syncthreads();

    const float4* x4 = (const float4*)(x + (size_t)bt * VV);
    for (int i = tid; i < VV / 4; i += 256) {
        float4 v = x4[i];
        if (v.x != 0.f) { int p = atomicAdd(&s_cnt, 1); if (p < 256) { s_idx[p] = 4*i+0; s_val[p] = v.x; } }
        if (v.y != 0.f) { int p = atomicAdd(&s_cnt, 1); if (p < 256) { s_idx[p] = 4*i+1; s_val[p] = v.y; } }
        if (v.z != 0.f) { int p = atomicAdd(&s_cnt, 1); if (p < 256) { s_idx[p] = 4*i+2; s_val[p] = v.z; } }
        if (v.w != 0.f) { int p = atomicAdd(&s_cnt, 1); if (p < 256) { s_idx[p] = 4*i+3; s_val[p] = v.w; } }
    }
    __syncthreads();
    int cnt = s_cnt; if (cnt > 256) cnt = 256;
    if (tid < DD) {
        float acc = 0.f;
        for (int i = 0; i < cnt; ++i)
            acc += s_val[i] * emb[(size_t)s_idx[i] * DD + tid];
        e[(size_t)bt * DD + tid] = acc;
        if (acc != 0.f) s_any = 1;
    }
    __syncthreads();
    if (tid == 0) mask[bt] = s_any;
}

// ---------------------------------------------------------------------------
// K2: input-side gates  x3[row, 0:384]=e@wih_f^T+bih_f ; x3[row,384:768]=e@wih_b^T+bih_b
// grid = 400 blocks (8 rows each), 256 threads; each thread 3 cols x 8 rows
// ---------------------------------------------------------------------------
__global__ __launch_bounds__(256) void k_gates(
    const float* __restrict__ e,
    const float* __restrict__ wih_f, const float* __restrict__ bih_f,
    const float* __restrict__ wih_b, const float* __restrict__ bih_b,
    float* __restrict__ x3)
{
    const int r0  = blockIdx.x * 8;
    const int tid = threadIdx.x;
    __shared__ __align__(16) float se[8][DD];
    for (int i = tid; i < 8 * DD; i += 256)
        se[i >> 7][i & 127] = e[(size_t)(r0 + (i >> 7)) * DD + (i & 127)];
    __syncthreads();

    for (int cc = 0; cc < 3; ++cc) {
        const int col = tid + cc * 256;                 // 0..767
        const float* wrow;
        float bias;
        if (col < G3) { wrow = wih_f + (size_t)col * DD;        bias = bih_f[col]; }
        else          { wrow = wih_b + (size_t)(col - G3) * DD; bias = bih_b[col - G3]; }
        float acc[8];
        #pragma unroll
        for (int r = 0; r < 8; ++r) acc[r] = 0.f;
        const float4* w4 = (const float4*)wrow;
        for (int k4 = 0; k4 < DD / 4; ++k4) {
            float4 w = w4[k4];
            #pragma unroll
            for (int r = 0; r < 8; ++r) {
                float4 ev = *(const float4*)&se[r][4 * k4];
                acc[r] += ev.x * w.x + ev.y * w.y + ev.z * w.z + ev.w * w.w;
            }
        }
        #pragma unroll
        for (int r = 0; r < 8; ++r)
            x3[(size_t)(r0 + r) * 768 + col] = acc[r] + bias;
    }
}

// ---------------------------------------------------------------------------
// K3: GRU v4. One block per (batch, dir). 512 threads = (g in 0..127) x (k-quarter).
// History: v1/v2 array weights -> scratch (VGPR 84/92). v3 named float4s ->
// REMATERIALIZED: VGPR_Count=116 < 192 weight floats, loads re-issued every
// timestep (~192 KB/block/step from L2 = the bottleneck).
// v4: (a) 96 weight floats/thread (24 named float4s, ~130 VGPR need vs 256
// budget), (b) asm "+v" pass-through makes the values asm-defined =>
// rematerialization is IMPOSSIBLE; allocator must keep them in VGPRs.
// (c) one-step x3 prefetch hides HBM latency under the previous step.
// DS/step unchanged: 8 waves x 8 ds_read_b128 (wave-uniform broadcast).
// ---------------------------------------------------------------------------
__global__ __launch_bounds__(512, 2) void k_gru(
    const float* __restrict__ x3,
    const float* __restrict__ whh_f, const float* __restrict__ bhh_f,
    const float* __restrict__ whh_b, const float* __restrict__ bhh_b,
    float* __restrict__ h_all)
{
    const int dir = blockIdx.x & 1;
    const int b   = blockIdx.x >> 1;
    const int tid = threadIdx.x;       // 0..511
    const int g   = tid & 127;         // output dim
    const int kq  = tid >> 7;          // k-quarter: 0..3
    const int kb  = kq * 32;           // k base
    const float* whh = dir ? whh_b : whh_f;
    const float* bhh = dir ? bhh_b : bhh_f;

    const float4* pr4 = (const float4*)(whh + (size_t)(g         ) * DD + kb);
    const float4* pz4 = (const float4*)(whh + (size_t)(DD     + g) * DD + kb);
    const float4* pn4 = (const float4*)(whh + (size_t)(2 * DD + g) * DD + kb);

#define Q8(M) M(0) M(1) M(2) M(3) M(4) M(5) M(6) M(7)
#define DECLW(i) float4 wr##i = pr4[i], wz##i = pz4[i], wn##i = pn4[i];
    Q8(DECLW)
    // Forbid rematerialization: asm-defined values must stay in VGPRs.
#define KEEP(i) asm("" : "+v"(wr##i.x), "+v"(wr##i.y), "+v"(wr##i.z), "+v"(wr##i.w), \
                         "+v"(wz##i.x), "+v"(wz##i.y), "+v"(wz##i.z), "+v"(wz##i.w), \
                         "+v"(wn##i.x), "+v"(wn##i.y), "+v"(wn##i.z), "+v"(wn##i.w));
    Q8(KEEP)
#undef KEEP

    float bhr = 0.f, bhz = 0.f, bhn = 0.f;
    if (tid < DD) { bhr = bhh[g]; bhz = bhh[DD + g]; bhn = bhh[2 * DD + g]; }

    __shared__ __align__(16) float h_lds[DD];
    __shared__ float p_lds[9 * DD];    // [(kq-1)*3 + gate][g]
    float h_reg = 0.f;
    if (tid < DD) h_lds[tid] = 0.f;

    // prefetch x3 for t=0
    float xr = 0.f, xz = 0.f, xn = 0.f;
    {
        const float* x3p = x3 + (size_t)(b * TT + (dir ? TT - 1 : 0)) * 768 + dir * G3;
        if (tid < DD) { xr = x3p[g]; xz = x3p[DD + g]; xn = x3p[2 * DD + g]; }
    }
    __syncthreads();

    for (int t = 0; t < TT; ++t) {
        const int te = dir ? (TT - 1 - t) : t;

        // prefetch x3 for t+1 (hidden under this step's dot + barriers)
        float nxr = 0.f, nxz = 0.f, nxn = 0.f;
        if (t + 1 < TT) {
            const int tn = dir ? (TT - 2 - t) : (t + 1);
            const float* x3n = x3 + (size_t)(b * TT + tn) * 768 + dir * G3;
            if (tid < DD) { nxr = x3n[g]; nxz = x3n[DD + g]; nxn = x3n[2 * DD + g]; }
        }

        // partial dots over this thread's k-quarter; 6 independent chains
        float ar0 = 0.f, ar1 = 0.f, az0 = 0.f, az1 = 0.f, an0 = 0.f, an1 = 0.f;
#define FMA(i) { float4 hv = *(const float4*)&h_lds[kb + 4 * (i)]; \
        (((i)&1) ? ar1 : ar0) += wr##i.x*hv.x + wr##i.y*hv.y + wr##i.z*hv.z + wr##i.w*hv.w; \
        (((i)&1) ? az1 : az0) += wz##i.x*hv.x + wz##i.y*hv.y + wz##i.z*hv.z + wz##i.w*hv.w; \
        (((i)&1) ? an1 : an0) += wn##i.x*hv.x + wn##i.y*hv.y + wn##i.z*hv.z + wn##i.w*hv.w; }
        Q8(FMA)
#undef FMA
        const float pr = ar0 + ar1, pz = az0 + az1, pn = an0 + an1;

        if (kq) {
            const int q = (kq - 1) * 3;
            p_lds[(q + 0) * DD + g] = pr;
            p_lds[(q + 1) * DD + g] = pz;
            p_lds[(q + 2) * DD + g] = pn;
        }
        __syncthreads();

        if (tid < DD) {
            float hr = pr + p_lds[0*DD+g] + p_lds[3*DD+g] + p_lds[6*DD+g] + bhr;
            float hz = pz + p_lds[1*DD+g] + p_lds[4*DD+g] + p_lds[7*DD+g] + bhz;
            float hn = pn + p_lds[2*DD+g] + p_lds[5*DD+g] + p_lds[8*DD+g] + bhn;
            float r  = __builtin_amdgcn_rcpf(1.f + __expf(-(xr + hr)));
            float z  = __builtin_amdgcn_rcpf(1.f + __expf(-(xz + hz)));
            // tanh(x) = 1 - 2/(e^(2x)+1): safe at +/-inf
            float e2 = __expf(2.f * (xn + r * hn));
            float n  = 1.f - 2.f * __builtin_amdgcn_rcpf(e2 + 1.f);
            float hnew = n + z * (h_reg - n);            // == (1-z)*n + z*h
            h_reg = hnew;
            h_lds[g] = hnew;
            h_all[(size_t)((dir * BB + b) * TT + te) * DD + g] = hnew;
        }
        __syncthreads();
        xr = nxr; xz = nxz; xn = nxn;
    }
#undef DECLW
#undef Q8
}

// ---------------------------------------------------------------------------
// K4a: per-batch attention + h_last + combine -> feat[b,128]
// ---------------------------------------------------------------------------
__global__ __launch_bounds__(256) void k_attn(
    const float* __restrict__ h_all, const int* __restrict__ mask,
    const float* __restrict__ attn_w, const float* __restrict__ attn_b,
    const float* __restrict__ comb_w, const float* __restrict__ comb_b,
    float* __restrict__ feat)
{
    const int b   = blockIdx.x;
    const int tid = threadIdx.x;
    __shared__ float s_aw[256];
    __shared__ float s_sc[128];
    __shared__ int   s_m[128];
    __shared__ float s_red[128];
    __shared__ __align__(16) float s_ch[512];

    s_aw[tid] = attn_w[tid];
    int m = 0;
    if (tid < 128) {
        m = (tid < TT) ? mask[b * TT + tid] : 0;
        s_m[tid] = m;
    }
    __syncthreads();
    for (int s = 64; s > 0; s >>= 1) {
        if (tid < s) s_m[tid] += s_m[tid + s];
        __syncthreads();
    }
    const int last = s_m[0] - 1;

    const float* hf = h_all + (size_t)(0 * BB + b) * TT * DD;
    const float* hb = h_all + (size_t)(1 * BB + b) * TT * DD;

    float sc = -1e9f;
    if (tid < TT) {
        float a = attn_b[0];
        const float4* hf4 = (const float4*)(hf + (size_t)tid * DD);
        const float4* hb4 = (const float4*)(hb + (size_t)tid * DD);
        for (int k = 0; k < DD / 4; ++k) {
            float4 v = hf4[k];
            a += v.x * s_aw[4*k] + v.y * s_aw[4*k+1] + v.z * s_aw[4*k+2] + v.w * s_aw[4*k+3];
        }
        for (int k = 0; k < DD / 4; ++k) {
            float4 v = hb4[k];
            a += v.x * s_aw[DD+4*k] + v.y * s_aw[DD+4*k+1] + v.z * s_aw[DD+4*k+2] + v.w * s_aw[DD+4*k+3];
        }
        sc = m ? a : -1e9f;
    }
    if (tid < 128) { s_sc[tid] = sc; s_red[tid] = sc; }
    __syncthreads();
    for (int s = 64; s > 0; s >>= 1) {
        if (tid < s) s_red[tid] = fmaxf(s_red[tid], s_red[tid + s]);
        __syncthreads();
    }
    const float mx = s_red[0];
    __syncthreads();
    float ex = 0.f;
    if (tid < 128) { ex = __expf(s_sc[tid] - mx); s_sc[tid] = ex; s_red[tid] = ex; }
    __syncthreads();
    for (int s = 64; s > 0; s >>= 1) {
        if (tid < s) s_red[tid] += s_red[tid + s];
        __syncthreads();
    }
    const float inv = 1.f / s_red[0];
    __syncthreads();

    {
        const int fl = tid & 127;
        const float* hp = (tid < 128) ? hf : hb;
        float csum = 0.f;
        for (int t = 0; t < TT; ++t)
            csum += s_sc[t] * hp[(size_t)t * DD + fl];
        s_ch[tid]       = csum * inv;
        s_ch[256 + tid] = hp[(size_t)last * DD + fl];
    }
    __syncthreads();

    if (tid < 128) {
        float a = comb_b[tid];
        const float4* cw = (const float4*)(comb_w + (size_t)tid * 512);
        for (int k = 0; k < 128; ++k) {
            float4 w4 = cw[k];
            float4 v4 = *(const float4*)&s_ch[4 * k];
            a += w4.x * v4.x + w4.y * v4.y + w4.z * v4.z + w4.w * v4.w;
        }
        feat[(size_t)b * DD + tid] = tanhf(a);
    }
}

// ---------------------------------------------------------------------------
// K4b: logits = feat @ fc_w^T + fc_b   grid = B*4 blocks, 256 threads
// ---------------------------------------------------------------------------
__global__ __launch_bounds__(256) void k_logits(
    const float* __restrict__ feat, const float* __restrict__ fc_w,
    const float* __restrict__ fc_b, float* __restrict__ out)
{
    const int b   = blockIdx.x >> 2;
    const int oc  = blockIdx.x & 3;
    const int tid = threadIdx.x;
    const int o   = oc * 256 + tid;
    __shared__ __align__(16) float s_f[DD];
    if (tid < DD) s_f[tid] = feat[(size_t)b * DD + tid];
    __syncthreads();
    if (o < OUTN) {
        float a = fc_b[o];
        const float4* w4 = (const float4*)(fc_w + (size_t)o * DD);
        for (int k = 0; k < DD / 4; ++k) {
            float4 w = w4[k];
            float4 v = *(const float4*)&s_f[4 * k];
            a += w.x * v.x + w.y * v.y + w.z * v.z + w.w * v.w;
        }
        out[(size_t)b * OUTN + o] = a;
    }
}

// ---------------------------------------------------------------------------
extern "C" void kernel_launch(void* const* d_in, const int* in_sizes, int n_in,
                              void* d_out, int out_size, void* d_ws, size_t ws_size,
                              hipStream_t stream)
{
    const float* x      = (const float*)d_in[0];
    const float* emb    = (const float*)d_in[1];
    const float* wih_f  = (const float*)d_in[2];
    const float* whh_f  = (const float*)d_in[3];
    const float* bih_f  = (const float*)d_in[4];
    const float* bhh_f  = (const float*)d_in[5];
    const float* wih_b  = (const float*)d_in[6];
    const float* whh_b  = (const float*)d_in[7];
    const float* bih_b  = (const float*)d_in[8];
    const float* bhh_b  = (const float*)d_in[9];
    const float* attn_w = (const float*)d_in[10];
    const float* attn_b = (const float*)d_in[11];
    const float* comb_w = (const float*)d_in[12];
    const float* comb_b = (const float*)d_in[13];
    const float* fc_w   = (const float*)d_in[14];
    const float* fc_b   = (const float*)d_in[15];
    float* out = (float*)d_out;

    // workspace layout (floats)
    float* ws    = (float*)d_ws;
    float* e     = ws;                    // 409600
    int*   mask  = (int*)(ws + 409600);   // 3200
    float* x3    = ws + 412800;           // 2457600
    float* h_all = ws + 2870400;          // 819200
    float* feat  = ws + 3689600;          // 4096   (total ~14.1 MB)

    k_embed <<<BB * TT,      256, 0, stream>>>(x, emb, e, mask);
    k_gates <<<(BB * TT)/8,  256, 0, stream>>>(e, wih_f, bih_f, wih_b, bih_b, x3);
    k_gru   <<<2 * BB,       512, 0, stream>>>(x3, whh_f, bhh_f, whh_b, bhh_b, h_all);
    k_attn  <<<BB,           256, 0, stream>>>(h_all, mask, attn_w, attn_b, comb_w, comb_b, feat);
    k_logits<<<BB * 4,       256, 0, stream>>>(feat, fc_w, fc_b, out);
}